// Round 1
// baseline (1529.552 us; speedup 1.0000x reference)
//
#include <hip/hip_runtime.h>

#define NCOL 64

// ---------------- degree / dinv / counts ----------------

__global__ void deg_kernel(const int* __restrict__ dst, int* __restrict__ degi, int ne) {
  int i = blockIdx.x * blockDim.x + threadIdx.x;
  int stride = gridDim.x * blockDim.x;
  for (; i < ne; i += stride) atomicAdd(&degi[dst[i]], 1);
}

__global__ void dinv_kernel(const int* __restrict__ degi, float* __restrict__ dinv, int n) {
  int i = blockIdx.x * blockDim.x + threadIdx.x;
  if (i < n) dinv[i] = rsqrtf((float)degi[i] + 1.0f);
}

__global__ void cnt_kernel(const int* __restrict__ batch, float* __restrict__ cnt, int n) {
  int i = blockIdx.x * blockDim.x + threadIdx.x;
  if (i < n) atomicAdd(&cnt[batch[i]], 1.0f);
}

// ---------------- tall-skinny GEMM, fused row-scale by dinv ----------------
// Y[i,:] = (X[i,:] @ W) * dinv[i];  W is [K][64] row-major, uniform -> s_loads.

template<int K>
__global__ void gemm_scaled(const float* __restrict__ X, const float* __restrict__ W,
                            const float* __restrict__ dinv, float* __restrict__ Y, int n) {
  int i = blockIdx.x * blockDim.x + threadIdx.x;
  if (i >= n) return;
  const float* xr = X + (size_t)i * K;
  float acc[NCOL];
#pragma unroll
  for (int c = 0; c < NCOL; ++c) acc[c] = 0.f;
#pragma unroll 2
  for (int k = 0; k < K; k += 4) {
    float4 xv = *reinterpret_cast<const float4*>(xr + k);
#pragma unroll
    for (int kk = 0; kk < 4; ++kk) {
      float xk = (kk == 0) ? xv.x : (kk == 1) ? xv.y : (kk == 2) ? xv.z : xv.w;
      const float* wr = W + (size_t)(k + kk) * NCOL;
#pragma unroll
      for (int c = 0; c < NCOL; c += 4) {
        float4 wv = *reinterpret_cast<const float4*>(wr + c);
        acc[c + 0] = fmaf(xk, wv.x, acc[c + 0]);
        acc[c + 1] = fmaf(xk, wv.y, acc[c + 1]);
        acc[c + 2] = fmaf(xk, wv.z, acc[c + 2]);
        acc[c + 3] = fmaf(xk, wv.w, acc[c + 3]);
      }
    }
  }
  float d = dinv[i];
  float* yr = Y + (size_t)i * NCOL;
#pragma unroll
  for (int c = 0; c < NCOL; c += 4) {
    float4 o;
    o.x = acc[c + 0] * d; o.y = acc[c + 1] * d;
    o.z = acc[c + 2] * d; o.w = acc[c + 3] * d;
    *reinterpret_cast<float4*>(yr + c) = o;
  }
}

// ---------------- edge scatter-add: S[dst,:] += Y[src,:] ----------------
// one 64-lane wave per edge; lane = column. src/dst wave-uniform -> scalar.

__global__ void scatter_kernel(const int* __restrict__ src, const int* __restrict__ dst,
                               const float* __restrict__ Y, float* __restrict__ S, int ne) {
  int c = threadIdx.x & 63;
  int e = (blockIdx.x * blockDim.x + threadIdx.x) >> 6;
  int estride = (gridDim.x * blockDim.x) >> 6;
  for (; e < ne; e += estride) {
    int es = __builtin_amdgcn_readfirstlane(src[e]);
    int ed = __builtin_amdgcn_readfirstlane(dst[e]);
    atomicAdd(&S[(size_t)ed * NCOL + c], Y[(size_t)es * NCOL + c]);
  }
}

// ---------------- layer-1 finalize: A = relu(dinv*(A+B) + b1) ----------------

__global__ void finalize1(float* __restrict__ A, const float* __restrict__ B,
                          const float* __restrict__ dinv, const float* __restrict__ b1, int n) {
  int t = blockIdx.x * blockDim.x + threadIdx.x;   // over n*16 float4 groups
  int total = n * (NCOL / 4);
  int stride = gridDim.x * blockDim.x;
  for (; t < total; t += stride) {
    int nd = t >> 4;
    int c4 = (t & 15) * 4;
    float d = dinv[nd];
    float4 a = reinterpret_cast<float4*>(A)[t];
    float4 b = reinterpret_cast<const float4*>(B)[t];
    float4 bb = *reinterpret_cast<const float4*>(b1 + c4);
    float4 r;
    r.x = fmaxf(fmaf(d, a.x + b.x, bb.x), 0.f);
    r.y = fmaxf(fmaf(d, a.y + b.y, bb.y), 0.f);
    r.z = fmaxf(fmaf(d, a.z + b.z, bb.z), 0.f);
    r.w = fmaxf(fmaf(d, a.w + b.w, bb.w), 0.f);
    reinterpret_cast<float4*>(A)[t] = r;
  }
}

// ---------------- pooling: pool[g,:] += dinv*(A+B)+b2 over sorted batch ----------------
// 64-lane group walks NPG contiguous nodes, register-accumulates per graph run.

#define NPG 64

__global__ void pool_kernel(const float* __restrict__ A, const float* __restrict__ B,
                            const float* __restrict__ dinv, const float* __restrict__ b2,
                            const int* __restrict__ batch, float* __restrict__ pool, int n) {
  int gid = (blockIdx.x * blockDim.x + threadIdx.x) >> 6;
  int c = threadIdx.x & 63;
  int n0 = gid * NPG;
  if (n0 >= n) return;
  int n1 = min(n0 + NPG, n);
  float bc = b2[c];
  float acc = 0.f;
  int curg = batch[n0];
  for (int nd = n0; nd < n1; ++nd) {
    int g = batch[nd];
    if (g != curg) {
      atomicAdd(&pool[(size_t)curg * NCOL + c], acc);
      acc = 0.f;
      curg = g;
    }
    size_t off = (size_t)nd * NCOL + c;
    acc += fmaf(dinv[nd], A[off] + B[off], bc);
  }
  atomicAdd(&pool[(size_t)curg * NCOL + c], acc);
}

// ---------------- final tiny GEMM: out = (pool/cnt) @ Wl + bl ----------------

__global__ void final_kernel(const float* __restrict__ pool, const float* __restrict__ cnt,
                             const float* __restrict__ Wl, const float* __restrict__ bl,
                             float* __restrict__ out, int ng) {
  int t = threadIdx.x;
  if (t >= ng * 6) return;
  int g = t / 6, o = t % 6;
  float inv = 1.0f / fmaxf(cnt[g], 1.0f);
  float s = 0.f;
#pragma unroll
  for (int c = 0; c < NCOL; ++c) s += pool[(size_t)g * NCOL + c] * Wl[c * 6 + o];
  out[t] = fmaf(s, inv, bl[o]);
}

// ---------------- launch ----------------

extern "C" void kernel_launch(void* const* d_in, const int* in_sizes, int n_in,
                              void* d_out, int out_size, void* d_ws, size_t ws_size,
                              hipStream_t stream) {
  const float* x    = (const float*)d_in[0];
  const int*   ei   = (const int*)d_in[1];
  const int*   batch= (const int*)d_in[2];
  const float* W1   = (const float*)d_in[3];
  const float* b1   = (const float*)d_in[4];
  const float* W2   = (const float*)d_in[5];
  const float* b2   = (const float*)d_in[6];
  const float* Wl   = (const float*)d_in[7];
  const float* bl   = (const float*)d_in[8];
  float* out = (float*)d_out;

  int n  = in_sizes[0] / 128;   // 100000
  int ne = in_sizes[1] / 2;     // 1600000
  int ng = out_size / 6;        // 64
  const int* srcI = ei;
  const int* dstI = ei + ne;

  char* w = (char*)d_ws;
  size_t o = 0;
  auto take = [&](size_t bytes) -> char* {
    char* p = w + o;
    o = (o + bytes + 255) & ~(size_t)255;
    return p;
  };
  float* dinv = (float*)take((size_t)n * 4);
  int*   degi = (int*)  take((size_t)n * 4);
  float* A    = (float*)take((size_t)n * NCOL * 4);
  float* B    = (float*)take((size_t)n * NCOL * 4);
  float* pool = (float*)take(4096 * 4 + 256);   // pool[64*64] then cnt[64], contiguous
  float* cnt  = pool + 4096;

  // zero the accumulators
  hipMemsetAsync(degi, 0, (size_t)n * 4, stream);
  hipMemsetAsync(pool, 0, 4096 * 4 + 256, stream);
  hipMemsetAsync(B, 0, (size_t)n * NCOL * 4, stream);

  int nb256 = (n + 255) / 256;

  deg_kernel<<<1024, 256, 0, stream>>>(dstI, degi, ne);
  cnt_kernel<<<nb256, 256, 0, stream>>>(batch, cnt, n);
  dinv_kernel<<<nb256, 256, 0, stream>>>(degi, dinv, n);

  // layer 1
  gemm_scaled<128><<<nb256, 256, 0, stream>>>(x, W1, dinv, A, n);
  scatter_kernel<<<8192, 256, 0, stream>>>(srcI, dstI, A, B, ne);
  finalize1<<<4096, 256, 0, stream>>>(A, B, dinv, b1, n);

  // layer 2
  gemm_scaled<64><<<nb256, 256, 0, stream>>>(A, W2, dinv, B, n);
  hipMemsetAsync(A, 0, (size_t)n * NCOL * 4, stream);
  scatter_kernel<<<8192, 256, 0, stream>>>(srcI, dstI, B, A, ne);

  // pool + head
  int ngroups = (n + NPG - 1) / NPG;
  int pblocks = (ngroups * 64 + 255) / 256;
  pool_kernel<<<pblocks, 256, 0, stream>>>(A, B, dinv, b2, batch, pool, n);
  final_kernel<<<1, 384, 0, stream>>>(pool, cnt, Wl, bl, out, ng);
}

// Round 2
// 896.528 us; speedup vs baseline: 1.7061x; 1.7061x over previous
//
#include <hip/hip_runtime.h>

#define NCOL 64

// ---------------- degree / dinv ----------------

__global__ void deg_kernel(const int* __restrict__ dst, int* __restrict__ degi, int ne) {
  int i = blockIdx.x * blockDim.x + threadIdx.x;
  int stride = gridDim.x * blockDim.x;
  for (; i < ne; i += stride) atomicAdd(&degi[dst[i]], 1);
}

__global__ void dinv_kernel(const int* __restrict__ degi, float* __restrict__ dinv, int n) {
  int i = blockIdx.x * blockDim.x + threadIdx.x;
  if (i < n) dinv[i] = rsqrtf((float)degi[i] + 1.0f);
}

// ---------------- graph-run boundaries (batch is SORTED -> no atomics) ----------------

__global__ void bounds_kernel(const int* __restrict__ batch, int* __restrict__ startg,
                              int* __restrict__ endg, int n) {
  int i = blockIdx.x * blockDim.x + threadIdx.x;
  if (i >= n) return;
  int b = batch[i];
  if (i == 0) {
    startg[b] = 0;
  } else {
    int bp = batch[i - 1];
    if (b != bp) { startg[b] = i; endg[bp] = i; }
  }
  if (i == n - 1) endg[b] = n;
}

// ---------------- tall-skinny GEMM, fused row-scale by dinv ----------------
// Y[i,:] = (X[i,:] @ W) * dinv[i];  W is [K][64] row-major, uniform -> s_loads.

template<int K>
__global__ void gemm_scaled(const float* __restrict__ X, const float* __restrict__ W,
                            const float* __restrict__ dinv, float* __restrict__ Y, int n) {
  int i = blockIdx.x * blockDim.x + threadIdx.x;
  if (i >= n) return;
  const float* xr = X + (size_t)i * K;
  float acc[NCOL];
#pragma unroll
  for (int c = 0; c < NCOL; ++c) acc[c] = 0.f;
#pragma unroll 2
  for (int k = 0; k < K; k += 4) {
    float4 xv = *reinterpret_cast<const float4*>(xr + k);
#pragma unroll
    for (int kk = 0; kk < 4; ++kk) {
      float xk = (kk == 0) ? xv.x : (kk == 1) ? xv.y : (kk == 2) ? xv.z : xv.w;
      const float* wr = W + (size_t)(k + kk) * NCOL;
#pragma unroll
      for (int c = 0; c < NCOL; c += 4) {
        float4 wv = *reinterpret_cast<const float4*>(wr + c);
        acc[c + 0] = fmaf(xk, wv.x, acc[c + 0]);
        acc[c + 1] = fmaf(xk, wv.y, acc[c + 1]);
        acc[c + 2] = fmaf(xk, wv.z, acc[c + 2]);
        acc[c + 3] = fmaf(xk, wv.w, acc[c + 3]);
      }
    }
  }
  float d = dinv[i];
  float* yr = Y + (size_t)i * NCOL;
#pragma unroll
  for (int c = 0; c < NCOL; c += 4) {
    float4 o;
    o.x = acc[c + 0] * d; o.y = acc[c + 1] * d;
    o.z = acc[c + 2] * d; o.w = acc[c + 3] * d;
    *reinterpret_cast<float4*>(yr + c) = o;
  }
}

// ---------------- edge scatter-add: S[dst,:] += Y[src,:] ----------------
// one 64-lane wave per edge; lane = column. src/dst wave-uniform -> scalar.

__global__ void scatter_kernel(const int* __restrict__ src, const int* __restrict__ dst,
                               const float* __restrict__ Y, float* __restrict__ S, int ne) {
  int c = threadIdx.x & 63;
  int e = (blockIdx.x * blockDim.x + threadIdx.x) >> 6;
  int estride = (gridDim.x * blockDim.x) >> 6;
  for (; e < ne; e += estride) {
    int es = __builtin_amdgcn_readfirstlane(src[e]);
    int ed = __builtin_amdgcn_readfirstlane(dst[e]);
    atomicAdd(&S[(size_t)ed * NCOL + c], Y[(size_t)es * NCOL + c]);
  }
}

// ---------------- layer-1 finalize: A = relu(dinv*(A+B) + b1) ----------------

__global__ void finalize1(float* __restrict__ A, const float* __restrict__ B,
                          const float* __restrict__ dinv, const float* __restrict__ b1, int n) {
  int t = blockIdx.x * blockDim.x + threadIdx.x;   // over n*16 float4 groups
  int total = n * (NCOL / 4);
  int stride = gridDim.x * blockDim.x;
  for (; t < total; t += stride) {
    int nd = t >> 4;
    int c4 = (t & 15) * 4;
    float d = dinv[nd];
    float4 a = reinterpret_cast<float4*>(A)[t];
    float4 b = reinterpret_cast<const float4*>(B)[t];
    float4 bb = *reinterpret_cast<const float4*>(b1 + c4);
    float4 r;
    r.x = fmaxf(fmaf(d, a.x + b.x, bb.x), 0.f);
    r.y = fmaxf(fmaf(d, a.y + b.y, bb.y), 0.f);
    r.z = fmaxf(fmaf(d, a.z + b.z, bb.z), 0.f);
    r.w = fmaxf(fmaf(d, a.w + b.w, bb.w), 0.f);
    reinterpret_cast<float4*>(A)[t] = r;
  }
}

// ---------------- pooling: pool[g,:] += dinv*(A+B)+b2 over sorted batch ----------------
// 64-lane group walks NPG contiguous nodes, register-accumulates per graph run.

#define NPG 64

__global__ void pool_kernel(const float* __restrict__ A, const float* __restrict__ B,
                            const float* __restrict__ dinv, const float* __restrict__ b2,
                            const int* __restrict__ batch, float* __restrict__ pool, int n) {
  int gid = (blockIdx.x * blockDim.x + threadIdx.x) >> 6;
  int c = threadIdx.x & 63;
  int n0 = gid * NPG;
  if (n0 >= n) return;
  int n1 = min(n0 + NPG, n);
  float bc = b2[c];
  float acc = 0.f;
  int curg = batch[n0];
  for (int nd = n0; nd < n1; ++nd) {
    int g = batch[nd];
    if (g != curg) {
      atomicAdd(&pool[(size_t)curg * NCOL + c], acc);
      acc = 0.f;
      curg = g;
    }
    size_t off = (size_t)nd * NCOL + c;
    acc += fmaf(dinv[nd], A[off] + B[off], bc);
  }
  atomicAdd(&pool[(size_t)curg * NCOL + c], acc);
}

// ---------------- final tiny GEMM: out = (pool/cnt) @ Wl + bl ----------------

__global__ void final_kernel(const float* __restrict__ pool, const int* __restrict__ startg,
                             const int* __restrict__ endg, const float* __restrict__ Wl,
                             const float* __restrict__ bl, float* __restrict__ out, int ng) {
  int t = threadIdx.x;
  if (t >= ng * 6) return;
  int g = t / 6, o = t % 6;
  float cntf = (float)(endg[g] - startg[g]);
  float inv = 1.0f / fmaxf(cntf, 1.0f);
  float s = 0.f;
#pragma unroll
  for (int c = 0; c < NCOL; ++c) s += pool[(size_t)g * NCOL + c] * Wl[c * 6 + o];
  out[t] = fmaf(s, inv, bl[o]);
}

// ---------------- launch ----------------

extern "C" void kernel_launch(void* const* d_in, const int* in_sizes, int n_in,
                              void* d_out, int out_size, void* d_ws, size_t ws_size,
                              hipStream_t stream) {
  const float* x    = (const float*)d_in[0];
  const int*   ei   = (const int*)d_in[1];
  const int*   batch= (const int*)d_in[2];
  const float* W1   = (const float*)d_in[3];
  const float* b1   = (const float*)d_in[4];
  const float* W2   = (const float*)d_in[5];
  const float* b2   = (const float*)d_in[6];
  const float* Wl   = (const float*)d_in[7];
  const float* bl   = (const float*)d_in[8];
  float* out = (float*)d_out;

  int n  = in_sizes[0] / 128;   // 100000
  int ne = in_sizes[1] / 2;     // 1600000
  int ng = out_size / 6;        // 64
  const int* srcI = ei;
  const int* dstI = ei + ne;

  char* w = (char*)d_ws;
  size_t o = 0;
  auto take = [&](size_t bytes) -> char* {
    char* p = w + o;
    o = (o + bytes + 255) & ~(size_t)255;
    return p;
  };
  float* dinv   = (float*)take((size_t)n * 4);
  int*   degi   = (int*)  take((size_t)n * 4);
  float* A      = (float*)take((size_t)n * NCOL * 4);
  float* B      = (float*)take((size_t)n * NCOL * 4);
  float* pool   = (float*)take(4096 * 4);
  int*   startg = (int*)  take(64 * 4);
  int*   endg   = (int*)  take(64 * 4);

  // zero the accumulators
  hipMemsetAsync(degi, 0, (size_t)n * 4, stream);
  hipMemsetAsync(pool, 0, 4096 * 4, stream);
  hipMemsetAsync(startg, 0, 64 * 4, stream);
  hipMemsetAsync(endg, 0, 64 * 4, stream);
  hipMemsetAsync(B, 0, (size_t)n * NCOL * 4, stream);

  int nb256 = (n + 255) / 256;

  deg_kernel<<<1024, 256, 0, stream>>>(dstI, degi, ne);
  bounds_kernel<<<nb256, 256, 0, stream>>>(batch, startg, endg, n);
  dinv_kernel<<<nb256, 256, 0, stream>>>(degi, dinv, n);

  // layer 1
  gemm_scaled<128><<<nb256, 256, 0, stream>>>(x, W1, dinv, A, n);
  scatter_kernel<<<8192, 256, 0, stream>>>(srcI, dstI, A, B, ne);
  finalize1<<<4096, 256, 0, stream>>>(A, B, dinv, b1, n);

  // layer 2
  gemm_scaled<64><<<nb256, 256, 0, stream>>>(A, W2, dinv, B, n);
  hipMemsetAsync(A, 0, (size_t)n * NCOL * 4, stream);
  scatter_kernel<<<8192, 256, 0, stream>>>(srcI, dstI, B, A, ne);

  // pool + head
  int ngroups = (n + NPG - 1) / NPG;
  int pblocks = (ngroups * 64 + 255) / 256;
  pool_kernel<<<pblocks, 256, 0, stream>>>(A, B, dinv, b2, batch, pool, n);
  final_kernel<<<1, 384, 0, stream>>>(pool, startg, endg, Wl, bl, out, ng);
}

// Round 3
// 602.795 us; speedup vs baseline: 2.5374x; 1.4873x over previous
//
#include <hip/hip_runtime.h>

#define NCOL 64

// ---------------- degree ----------------

__global__ void deg_kernel(const int* __restrict__ dst, int* __restrict__ degi, int ne) {
  int i = blockIdx.x * blockDim.x + threadIdx.x;
  int stride = gridDim.x * blockDim.x;
  for (; i < ne; i += stride) atomicAdd(&degi[dst[i]], 1);
}

__global__ void dinv_kernel(const int* __restrict__ degi, float* __restrict__ dinv, int n) {
  int i = blockIdx.x * blockDim.x + threadIdx.x;
  if (i < n) dinv[i] = rsqrtf((float)degi[i] + 1.0f);
}

// ---------------- graph-run boundaries (batch is SORTED -> no atomics) ----------------

__global__ void bounds_kernel(const int* __restrict__ batch, int* __restrict__ startg,
                              int* __restrict__ endg, int n) {
  int i = blockIdx.x * blockDim.x + threadIdx.x;
  if (i >= n) return;
  int b = batch[i];
  if (i == 0) {
    startg[b] = 0;
  } else {
    int bp = batch[i - 1];
    if (b != bp) { startg[b] = i; endg[bp] = i; }
  }
  if (i == n - 1) endg[b] = n;
}

// ---------------- exclusive prefix scan of degrees -> rowptr[0..n] ----------------
// single block, 1024 threads, each owns a contiguous chunk.

__global__ void scan_kernel(const int* __restrict__ degi, int* __restrict__ rowptr, int n) {
  __shared__ int part[1024];
  int t = threadIdx.x;
  int chunk = (n + 1023) >> 10;
  int lo = t * chunk, hi = min(lo + chunk, n);
  int s = 0;
  for (int i = lo; i < hi; ++i) s += degi[i];
  part[t] = s;
  __syncthreads();
  // Hillis-Steele inclusive scan over 1024 partials
  for (int d = 1; d < 1024; d <<= 1) {
    int v = (t >= d) ? part[t - d] : 0;
    __syncthreads();
    part[t] += v;
    __syncthreads();
  }
  int off = part[t] - s;  // exclusive prefix for this chunk
  for (int i = lo; i < hi; ++i) { rowptr[i] = off; off += degi[i]; }
  if (t == 1023) rowptr[n] = off;
}

// ---------------- CSR fill: csr_src grouped by dst ----------------

__global__ void csr_fill(const int* __restrict__ src, const int* __restrict__ dst,
                         int* __restrict__ cursor, int* __restrict__ csr_src, int ne) {
  int i = blockIdx.x * blockDim.x + threadIdx.x;
  int stride = gridDim.x * blockDim.x;
  for (; i < ne; i += stride) {
    int pos = atomicAdd(&cursor[dst[i]], 1);
    csr_src[pos] = src[i];
  }
}

// ---------------- tall-skinny GEMM, fused row-scale by dinv ----------------
// Y[i,:] = (X[i,:] @ W) * dinv[i]

template<int K>
__global__ void gemm_scaled(const float* __restrict__ X, const float* __restrict__ W,
                            const float* __restrict__ dinv, float* __restrict__ Y, int n) {
  int i = blockIdx.x * blockDim.x + threadIdx.x;
  if (i >= n) return;
  const float* xr = X + (size_t)i * K;
  float acc[NCOL];
#pragma unroll
  for (int c = 0; c < NCOL; ++c) acc[c] = 0.f;
#pragma unroll 2
  for (int k = 0; k < K; k += 4) {
    float4 xv = *reinterpret_cast<const float4*>(xr + k);
#pragma unroll
    for (int kk = 0; kk < 4; ++kk) {
      float xk = (kk == 0) ? xv.x : (kk == 1) ? xv.y : (kk == 2) ? xv.z : xv.w;
      const float* wr = W + (size_t)(k + kk) * NCOL;
#pragma unroll
      for (int c = 0; c < NCOL; c += 4) {
        float4 wv = *reinterpret_cast<const float4*>(wr + c);
        acc[c + 0] = fmaf(xk, wv.x, acc[c + 0]);
        acc[c + 1] = fmaf(xk, wv.y, acc[c + 1]);
        acc[c + 2] = fmaf(xk, wv.z, acc[c + 2]);
        acc[c + 3] = fmaf(xk, wv.w, acc[c + 3]);
      }
    }
  }
  float d = dinv[i];
  float* yr = Y + (size_t)i * NCOL;
#pragma unroll
  for (int c = 0; c < NCOL; c += 4) {
    float4 o;
    o.x = acc[c + 0] * d; o.y = acc[c + 1] * d;
    o.z = acc[c + 2] * d; o.w = acc[c + 3] * d;
    *reinterpret_cast<float4*>(yr + c) = o;
  }
}

// ---------------- CSR gather-aggregate (replaces atomic scatter) ----------------
// wave per dst node, lane = column. H[nd] = act(dinv[nd]*(Y[nd] + sum Y[src]) + b)

template<bool RELU>
__global__ void aggregate(const int* __restrict__ rowptr, const int* __restrict__ csr_src,
                          const float* __restrict__ Y, const float* __restrict__ dinv,
                          const float* __restrict__ bias, float* __restrict__ H, int n) {
  int nd = (blockIdx.x * blockDim.x + threadIdx.x) >> 6;
  if (nd >= n) return;
  nd = __builtin_amdgcn_readfirstlane(nd);   // wave-uniform -> scalar loads below
  int c = threadIdx.x & 63;
  int lo = rowptr[nd], hi = rowptr[nd + 1];
  float acc = Y[(size_t)nd * NCOL + c];      // self-loop term
  int p = lo;
  int hi4 = lo + ((hi - lo) & ~3);
  for (; p < hi4; p += 4) {
    int s0 = csr_src[p], s1 = csr_src[p + 1], s2 = csr_src[p + 2], s3 = csr_src[p + 3];
    float a0 = Y[(size_t)s0 * NCOL + c];
    float a1 = Y[(size_t)s1 * NCOL + c];
    float a2 = Y[(size_t)s2 * NCOL + c];
    float a3 = Y[(size_t)s3 * NCOL + c];
    acc += a0; acc += a1; acc += a2; acc += a3;
  }
  for (; p < hi; ++p) acc += Y[(size_t)csr_src[p] * NCOL + c];
  float v = fmaf(dinv[nd], acc, bias[c]);
  if (RELU) v = fmaxf(v, 0.f);
  H[(size_t)nd * NCOL + c] = v;
}

// ---------------- pooling: pool[g,:] += H over sorted batch runs ----------------

#define NPG 64

__global__ void pool_kernel(const float* __restrict__ H, const int* __restrict__ batch,
                            float* __restrict__ pool, int n) {
  int gid = (blockIdx.x * blockDim.x + threadIdx.x) >> 6;
  int c = threadIdx.x & 63;
  int n0 = gid * NPG;
  if (n0 >= n) return;
  int n1 = min(n0 + NPG, n);
  float acc = 0.f;
  int curg = batch[n0];
  for (int nd = n0; nd < n1; ++nd) {
    int g = batch[nd];
    if (g != curg) {
      atomicAdd(&pool[(size_t)curg * NCOL + c], acc);
      acc = 0.f;
      curg = g;
    }
    acc += H[(size_t)nd * NCOL + c];
  }
  atomicAdd(&pool[(size_t)curg * NCOL + c], acc);
}

// ---------------- final tiny GEMM: out = (pool/cnt) @ Wl + bl ----------------

__global__ void final_kernel(const float* __restrict__ pool, const int* __restrict__ startg,
                             const int* __restrict__ endg, const float* __restrict__ Wl,
                             const float* __restrict__ bl, float* __restrict__ out, int ng) {
  int t = threadIdx.x;
  if (t >= ng * 6) return;
  int g = t / 6, o = t % 6;
  float cntf = (float)(endg[g] - startg[g]);
  float inv = 1.0f / fmaxf(cntf, 1.0f);
  float s = 0.f;
#pragma unroll
  for (int c = 0; c < NCOL; ++c) s += pool[(size_t)g * NCOL + c] * Wl[c * 6 + o];
  out[t] = fmaf(s, inv, bl[o]);
}

// ---------------- launch ----------------

extern "C" void kernel_launch(void* const* d_in, const int* in_sizes, int n_in,
                              void* d_out, int out_size, void* d_ws, size_t ws_size,
                              hipStream_t stream) {
  const float* x    = (const float*)d_in[0];
  const int*   ei   = (const int*)d_in[1];
  const int*   batch= (const int*)d_in[2];
  const float* W1   = (const float*)d_in[3];
  const float* b1   = (const float*)d_in[4];
  const float* W2   = (const float*)d_in[5];
  const float* b2   = (const float*)d_in[6];
  const float* Wl   = (const float*)d_in[7];
  const float* bl   = (const float*)d_in[8];
  float* out = (float*)d_out;

  int n  = in_sizes[0] / 128;   // 100000
  int ne = in_sizes[1] / 2;     // 1600000
  int ng = out_size / 6;        // 64
  const int* srcI = ei;
  const int* dstI = ei + ne;

  char* w = (char*)d_ws;
  size_t o = 0;
  auto take = [&](size_t bytes) -> char* {
    char* p = w + o;
    o = (o + bytes + 255) & ~(size_t)255;
    return p;
  };
  float* dinv    = (float*)take((size_t)n * 4);
  int*   degi    = (int*)  take((size_t)n * 4);   // reused as cursor after scan
  int*   rowptr  = (int*)  take((size_t)(n + 1) * 4);
  int*   csr_src = (int*)  take((size_t)ne * 4);
  float* Y       = (float*)take((size_t)n * NCOL * 4);
  float* H       = (float*)take((size_t)n * NCOL * 4);
  float* pool    = (float*)take(4096 * 4);
  int*   startg  = (int*)  take(64 * 4);
  int*   endg    = (int*)  take(64 * 4);
  int*   cursor  = degi;

  hipMemsetAsync(degi, 0, (size_t)n * 4, stream);
  hipMemsetAsync(pool, 0, 4096 * 4, stream);
  hipMemsetAsync(startg, 0, 64 * 4, stream);
  hipMemsetAsync(endg, 0, 64 * 4, stream);

  int nb256 = (n + 255) / 256;

  // CSR build (shared by both layers)
  deg_kernel<<<1024, 256, 0, stream>>>(dstI, degi, ne);
  bounds_kernel<<<nb256, 256, 0, stream>>>(batch, startg, endg, n);
  dinv_kernel<<<nb256, 256, 0, stream>>>(degi, dinv, n);
  scan_kernel<<<1, 1024, 0, stream>>>(degi, rowptr, n);
  hipMemcpyAsync(cursor, rowptr, (size_t)n * 4, hipMemcpyDeviceToDevice, stream);
  csr_fill<<<4096, 256, 0, stream>>>(srcI, dstI, cursor, csr_src, ne);

  int nbAgg = (n * 64 + 255) / 256;

  // layer 1: Y = (x@W1)*dinv ; H = relu(dinv*(Y_self + sum Y[src]) + b1)
  gemm_scaled<128><<<nb256, 256, 0, stream>>>(x, W1, dinv, Y, n);
  aggregate<true><<<nbAgg, 256, 0, stream>>>(rowptr, csr_src, Y, dinv, b1, H, n);

  // layer 2: Y = (H@W2)*dinv ; H2 = dinv*(Y_self + sum Y[src]) + b2  (reuse H)
  gemm_scaled<64><<<nb256, 256, 0, stream>>>(H, W2, dinv, Y, n);
  aggregate<false><<<nbAgg, 256, 0, stream>>>(rowptr, csr_src, Y, dinv, b2, H, n);

  // pool + head
  int ngroups = (n + NPG - 1) / NPG;
  int pblocks = (ngroups * 64 + 255) / 256;
  pool_kernel<<<pblocks, 256, 0, stream>>>(H, batch, pool, n);
  final_kernel<<<1, 384, 0, stream>>>(pool, startg, endg, Wl, bl, out, ng);
}

// Round 4
// 452.499 us; speedup vs baseline: 3.3802x; 1.3321x over previous
//
#include <hip/hip_runtime.h>

#define NCOL 64

// ---------------- degree ----------------

__global__ void deg_kernel(const int* __restrict__ dst, int* __restrict__ degi, int ne) {
  int i = blockIdx.x * blockDim.x + threadIdx.x;
  int stride = gridDim.x * blockDim.x;
  for (; i < ne; i += stride) atomicAdd(&degi[dst[i]], 1);
}

__global__ void dinv_kernel(const int* __restrict__ degi, float* __restrict__ dinv, int n) {
  int i = blockIdx.x * blockDim.x + threadIdx.x;
  if (i < n) dinv[i] = rsqrtf((float)degi[i] + 1.0f);
}

// ---------------- graph-run boundaries (batch is SORTED -> no atomics) ----------------

__global__ void bounds_kernel(const int* __restrict__ batch, int* __restrict__ startg,
                              int* __restrict__ endg, int n) {
  int i = blockIdx.x * blockDim.x + threadIdx.x;
  if (i >= n) return;
  int b = batch[i];
  if (i == 0) {
    startg[b] = 0;
  } else {
    int bp = batch[i - 1];
    if (b != bp) { startg[b] = i; endg[bp] = i; }
  }
  if (i == n - 1) endg[b] = n;
}

// ---------------- 3-pass exclusive scan of degrees -> rowptr[0..n] + cursor ----------------
// Pass A: per-thread partial sums (8 elems/thread, grid-wide).
// Pass B: 1-block scan over the 12.5k partials (13 elems/thread serial).
// Pass C: grid-wide fill of rowptr AND cursor copy.

#define SCAN_C 8

__global__ void scan_part(const int* __restrict__ degi, int* __restrict__ tsum,
                          int n, int nthreads) {
  int t = blockIdx.x * blockDim.x + threadIdx.x;
  if (t >= nthreads) return;
  int lo = t * SCAN_C, hi = min(lo + SCAN_C, n);
  int s = 0;
  for (int i = lo; i < hi; ++i) s += degi[i];
  tsum[t] = s;
}

__global__ void scan_mid(int* __restrict__ tsum, int* __restrict__ toff, int nthreads) {
  __shared__ int part[1024];
  int t = threadIdx.x;
  int chunk = (nthreads + 1023) >> 10;
  int lo = t * chunk, hi = min(lo + chunk, nthreads);
  int s = 0;
  for (int i = lo; i < hi; ++i) s += tsum[i];
  part[t] = s;
  __syncthreads();
  for (int d = 1; d < 1024; d <<= 1) {
    int v = (t >= d) ? part[t - d] : 0;
    __syncthreads();
    part[t] += v;
    __syncthreads();
  }
  int off = part[t] - s;
  for (int i = lo; i < hi; ++i) { toff[i] = off; off += tsum[i]; }
}

__global__ void scan_fill(const int* __restrict__ degi, const int* __restrict__ toff,
                          int* __restrict__ rowptr, int* __restrict__ cursor,
                          int n, int nthreads) {
  int t = blockIdx.x * blockDim.x + threadIdx.x;
  if (t >= nthreads) return;
  int lo = t * SCAN_C, hi = min(lo + SCAN_C, n);
  int off = toff[t];
  for (int i = lo; i < hi; ++i) {
    rowptr[i] = off;
    cursor[i] = off;
    off += degi[i];
  }
  if (hi == n) rowptr[n] = off;
}

// ---------------- CSR fill: csr_src grouped by dst ----------------

__global__ void csr_fill(const int* __restrict__ src, const int* __restrict__ dst,
                         int* __restrict__ cursor, int* __restrict__ csr_src, int ne) {
  int i = blockIdx.x * blockDim.x + threadIdx.x;
  int stride = gridDim.x * blockDim.x;
  for (; i < ne; i += stride) {
    int pos = atomicAdd(&cursor[dst[i]], 1);
    csr_src[pos] = src[i];
  }
}

// ---------------- tall-skinny GEMM, fused row-scale by dinv ----------------
// Y[i,:] = (X[i,:] @ W) * dinv[i]

template<int K>
__global__ void gemm_scaled(const float* __restrict__ X, const float* __restrict__ W,
                            const float* __restrict__ dinv, float* __restrict__ Y, int n) {
  int i = blockIdx.x * blockDim.x + threadIdx.x;
  if (i >= n) return;
  const float* xr = X + (size_t)i * K;
  float acc[NCOL];
#pragma unroll
  for (int c = 0; c < NCOL; ++c) acc[c] = 0.f;
#pragma unroll 2
  for (int k = 0; k < K; k += 4) {
    float4 xv = *reinterpret_cast<const float4*>(xr + k);
#pragma unroll
    for (int kk = 0; kk < 4; ++kk) {
      float xk = (kk == 0) ? xv.x : (kk == 1) ? xv.y : (kk == 2) ? xv.z : xv.w;
      const float* wr = W + (size_t)(k + kk) * NCOL;
#pragma unroll
      for (int c = 0; c < NCOL; c += 4) {
        float4 wv = *reinterpret_cast<const float4*>(wr + c);
        acc[c + 0] = fmaf(xk, wv.x, acc[c + 0]);
        acc[c + 1] = fmaf(xk, wv.y, acc[c + 1]);
        acc[c + 2] = fmaf(xk, wv.z, acc[c + 2]);
        acc[c + 3] = fmaf(xk, wv.w, acc[c + 3]);
      }
    }
  }
  float d = dinv[i];
  float* yr = Y + (size_t)i * NCOL;
#pragma unroll
  for (int c = 0; c < NCOL; c += 4) {
    float4 o;
    o.x = acc[c + 0] * d; o.y = acc[c + 1] * d;
    o.z = acc[c + 2] * d; o.w = acc[c + 3] * d;
    *reinterpret_cast<float4*>(yr + c) = o;
  }
}

// ---------------- CSR gather-aggregate ----------------
// wave per dst node, lane = column. H[nd] = act(dinv[nd]*(Y[nd] + sum Y[src]) + b)

template<bool RELU>
__global__ void aggregate(const int* __restrict__ rowptr, const int* __restrict__ csr_src,
                          const float* __restrict__ Y, const float* __restrict__ dinv,
                          const float* __restrict__ bias, float* __restrict__ H, int n) {
  int nd = (blockIdx.x * blockDim.x + threadIdx.x) >> 6;
  if (nd >= n) return;
  nd = __builtin_amdgcn_readfirstlane(nd);   // wave-uniform -> scalar loads below
  int c = threadIdx.x & 63;
  int lo = rowptr[nd], hi = rowptr[nd + 1];
  float acc = Y[(size_t)nd * NCOL + c];      // self-loop term
  int p = lo;
  int hi4 = lo + ((hi - lo) & ~3);
  for (; p < hi4; p += 4) {
    int s0 = csr_src[p], s1 = csr_src[p + 1], s2 = csr_src[p + 2], s3 = csr_src[p + 3];
    float a0 = Y[(size_t)s0 * NCOL + c];
    float a1 = Y[(size_t)s1 * NCOL + c];
    float a2 = Y[(size_t)s2 * NCOL + c];
    float a3 = Y[(size_t)s3 * NCOL + c];
    acc += a0; acc += a1; acc += a2; acc += a3;
  }
  for (; p < hi; ++p) acc += Y[(size_t)csr_src[p] * NCOL + c];
  float v = fmaf(dinv[nd], acc, bias[c]);
  if (RELU) v = fmaxf(v, 0.f);
  H[(size_t)nd * NCOL + c] = v;
}

// ---------------- pooling: pool[g,:] += H over sorted batch runs ----------------

#define NPG 64

__global__ void pool_kernel(const float* __restrict__ H, const int* __restrict__ batch,
                            float* __restrict__ pool, int n) {
  int gid = (blockIdx.x * blockDim.x + threadIdx.x) >> 6;
  int c = threadIdx.x & 63;
  int n0 = gid * NPG;
  if (n0 >= n) return;
  int n1 = min(n0 + NPG, n);
  float acc = 0.f;
  int curg = batch[n0];
  for (int nd = n0; nd < n1; ++nd) {
    int g = batch[nd];
    if (g != curg) {
      atomicAdd(&pool[(size_t)curg * NCOL + c], acc);
      acc = 0.f;
      curg = g;
    }
    acc += H[(size_t)nd * NCOL + c];
  }
  atomicAdd(&pool[(size_t)curg * NCOL + c], acc);
}

// ---------------- final tiny GEMM: out = (pool/cnt) @ Wl + bl ----------------

__global__ void final_kernel(const float* __restrict__ pool, const int* __restrict__ startg,
                             const int* __restrict__ endg, const float* __restrict__ Wl,
                             const float* __restrict__ bl, float* __restrict__ out, int ng) {
  int t = threadIdx.x;
  if (t >= ng * 6) return;
  int g = t / 6, o = t % 6;
  float cntf = (float)(endg[g] - startg[g]);
  float inv = 1.0f / fmaxf(cntf, 1.0f);
  float s = 0.f;
#pragma unroll
  for (int c = 0; c < NCOL; ++c) s += pool[(size_t)g * NCOL + c] * Wl[c * 6 + o];
  out[t] = fmaf(s, inv, bl[o]);
}

// ---------------- launch ----------------

extern "C" void kernel_launch(void* const* d_in, const int* in_sizes, int n_in,
                              void* d_out, int out_size, void* d_ws, size_t ws_size,
                              hipStream_t stream) {
  const float* x    = (const float*)d_in[0];
  const int*   ei   = (const int*)d_in[1];
  const int*   batch= (const int*)d_in[2];
  const float* W1   = (const float*)d_in[3];
  const float* b1   = (const float*)d_in[4];
  const float* W2   = (const float*)d_in[5];
  const float* b2   = (const float*)d_in[6];
  const float* Wl   = (const float*)d_in[7];
  const float* bl   = (const float*)d_in[8];
  float* out = (float*)d_out;

  int n  = in_sizes[0] / 128;   // 100000
  int ne = in_sizes[1] / 2;     // 1600000
  int ng = out_size / 6;        // 64
  const int* srcI = ei;
  const int* dstI = ei + ne;

  char* w = (char*)d_ws;
  size_t o = 0;
  auto take = [&](size_t bytes) -> char* {
    char* p = w + o;
    o = (o + bytes + 255) & ~(size_t)255;
    return p;
  };
  float* dinv    = (float*)take((size_t)n * 4);
  int*   degi    = (int*)  take((size_t)n * 4);
  int*   cursor  = (int*)  take((size_t)n * 4);
  int*   rowptr  = (int*)  take((size_t)(n + 1) * 4);
  int*   csr_src = (int*)  take((size_t)ne * 4);
  float* Y       = (float*)take((size_t)n * NCOL * 4);
  float* H       = (float*)take((size_t)n * NCOL * 4);
  float* pool    = (float*)take(4096 * 4);
  int*   startg  = (int*)  take(64 * 4);
  int*   endg    = (int*)  take(64 * 4);
  int*   tsum    = (int*)  take(16384 * 4);
  int*   toff    = (int*)  take(16384 * 4);

  hipMemsetAsync(degi, 0, (size_t)n * 4, stream);
  hipMemsetAsync(pool, 0, 4096 * 4, stream);
  hipMemsetAsync(startg, 0, 64 * 4, stream);
  hipMemsetAsync(endg, 0, 64 * 4, stream);

  int nb256 = (n + 255) / 256;
  int nthreads = (n + SCAN_C - 1) / SCAN_C;
  int nbScan = (nthreads + 255) / 256;

  // CSR build (shared by both layers)
  deg_kernel<<<1024, 256, 0, stream>>>(dstI, degi, ne);
  bounds_kernel<<<nb256, 256, 0, stream>>>(batch, startg, endg, n);
  dinv_kernel<<<nb256, 256, 0, stream>>>(degi, dinv, n);
  scan_part<<<nbScan, 256, 0, stream>>>(degi, tsum, n, nthreads);
  scan_mid<<<1, 1024, 0, stream>>>(tsum, toff, nthreads);
  scan_fill<<<nbScan, 256, 0, stream>>>(degi, toff, rowptr, cursor, n, nthreads);
  csr_fill<<<4096, 256, 0, stream>>>(srcI, dstI, cursor, csr_src, ne);

  int nbAgg = (n * 64 + 255) / 256;

  // layer 1: Y = (x@W1)*dinv ; H = relu(dinv*(Y_self + sum Y[src]) + b1)
  gemm_scaled<128><<<nb256, 256, 0, stream>>>(x, W1, dinv, Y, n);
  aggregate<true><<<nbAgg, 256, 0, stream>>>(rowptr, csr_src, Y, dinv, b1, H, n);

  // layer 2: Y = (H@W2)*dinv ; H2 = dinv*(Y_self + sum Y[src]) + b2  (reuse H)
  gemm_scaled<64><<<nb256, 256, 0, stream>>>(H, W2, dinv, Y, n);
  aggregate<false><<<nbAgg, 256, 0, stream>>>(rowptr, csr_src, Y, dinv, b2, H, n);

  // pool + head
  int ngroups = (n + NPG - 1) / NPG;
  int pblocks = (ngroups * 64 + 255) / 256;
  pool_kernel<<<pblocks, 256, 0, stream>>>(H, batch, pool, n);
  final_kernel<<<1, 384, 0, stream>>>(pool, startg, endg, Wl, bl, out, ng);
}

// Round 5
// 405.480 us; speedup vs baseline: 3.7722x; 1.1160x over previous
//
#include <hip/hip_runtime.h>

#define NCOL 64
#define NXCD 8

// ---------------- degree (XCD-partitioned by dst range: atomics stay L2-local) ----------------

__global__ void deg_part(const int* __restrict__ dst, int* __restrict__ degi,
                         int ne, int n) {
  int chunk = (n + NXCD - 1) / NXCD;
  int g = blockIdx.x & (NXCD - 1);
  int lo = g * chunk, hi = min(lo + chunk, n);
  int tid = (blockIdx.x >> 3) * blockDim.x + threadIdx.x;
  int stride = (gridDim.x >> 3) * blockDim.x;
  for (int i = tid; i < ne; i += stride) {
    int d = dst[i];
    if (d >= lo && d < hi) atomicAdd(&degi[d], 1);
  }
}

__global__ void dinv_kernel(const int* __restrict__ degi, float* __restrict__ dinv, int n) {
  int i = blockIdx.x * blockDim.x + threadIdx.x;
  if (i < n) dinv[i] = rsqrtf((float)degi[i] + 1.0f);
}

// ---------------- graph-run boundaries (batch is SORTED -> no atomics) ----------------

__global__ void bounds_kernel(const int* __restrict__ batch, int* __restrict__ startg,
                              int* __restrict__ endg, int n) {
  int i = blockIdx.x * blockDim.x + threadIdx.x;
  if (i >= n) return;
  int b = batch[i];
  if (i == 0) {
    startg[b] = 0;
  } else {
    int bp = batch[i - 1];
    if (b != bp) { startg[b] = i; endg[bp] = i; }
  }
  if (i == n - 1) endg[b] = n;
}

// ---------------- 3-pass exclusive scan of degrees -> rowptr[0..n] + cursor ----------------

#define SCAN_C 8

__global__ void scan_part(const int* __restrict__ degi, int* __restrict__ tsum,
                          int n, int nthreads) {
  int t = blockIdx.x * blockDim.x + threadIdx.x;
  if (t >= nthreads) return;
  int lo = t * SCAN_C, hi = min(lo + SCAN_C, n);
  int s = 0;
  for (int i = lo; i < hi; ++i) s += degi[i];
  tsum[t] = s;
}

__global__ void scan_mid(int* __restrict__ tsum, int* __restrict__ toff, int nthreads) {
  __shared__ int part[1024];
  int t = threadIdx.x;
  int chunk = (nthreads + 1023) >> 10;
  int lo = t * chunk, hi = min(lo + chunk, nthreads);
  int s = 0;
  for (int i = lo; i < hi; ++i) s += tsum[i];
  part[t] = s;
  __syncthreads();
  for (int d = 1; d < 1024; d <<= 1) {
    int v = (t >= d) ? part[t - d] : 0;
    __syncthreads();
    part[t] += v;
    __syncthreads();
  }
  int off = part[t] - s;
  for (int i = lo; i < hi; ++i) { toff[i] = off; off += tsum[i]; }
}

__global__ void scan_fill(const int* __restrict__ degi, const int* __restrict__ toff,
                          int* __restrict__ rowptr, int* __restrict__ cursor,
                          int n, int nthreads) {
  int t = blockIdx.x * blockDim.x + threadIdx.x;
  if (t >= nthreads) return;
  int lo = t * SCAN_C, hi = min(lo + SCAN_C, n);
  int off = toff[t];
  for (int i = lo; i < hi; ++i) {
    rowptr[i] = off;
    cursor[i] = off;
    off += degi[i];
  }
  if (hi == n) rowptr[n] = off;
}

// ---------------- CSR fill (XCD-partitioned: csr writes merge in local L2) ----------------

__global__ void csr_fill_part(const int* __restrict__ src, const int* __restrict__ dst,
                              int* __restrict__ cursor, int* __restrict__ csr_src,
                              int ne, int n) {
  int chunk = (n + NXCD - 1) / NXCD;
  int g = blockIdx.x & (NXCD - 1);
  int lo = g * chunk, hi = min(lo + chunk, n);
  int tid = (blockIdx.x >> 3) * blockDim.x + threadIdx.x;
  int stride = (gridDim.x >> 3) * blockDim.x;
  for (int i = tid; i < ne; i += stride) {
    int d = dst[i];
    if (d >= lo && d < hi) {
      int pos = atomicAdd(&cursor[d], 1);
      csr_src[pos] = src[i];
    }
  }
}

// ---------------- tall-skinny GEMM, fused row-scale by dinv ----------------
// Y[i,:] = (X[i,:] @ W) * dinv[i]

template<int K>
__global__ void gemm_scaled(const float* __restrict__ X, const float* __restrict__ W,
                            const float* __restrict__ dinv, float* __restrict__ Y, int n) {
  int i = blockIdx.x * blockDim.x + threadIdx.x;
  if (i >= n) return;
  const float* xr = X + (size_t)i * K;
  float acc[NCOL];
#pragma unroll
  for (int c = 0; c < NCOL; ++c) acc[c] = 0.f;
#pragma unroll 2
  for (int k = 0; k < K; k += 4) {
    float4 xv = *reinterpret_cast<const float4*>(xr + k);
#pragma unroll
    for (int kk = 0; kk < 4; ++kk) {
      float xk = (kk == 0) ? xv.x : (kk == 1) ? xv.y : (kk == 2) ? xv.z : xv.w;
      const float* wr = W + (size_t)(k + kk) * NCOL;
#pragma unroll
      for (int c = 0; c < NCOL; c += 4) {
        float4 wv = *reinterpret_cast<const float4*>(wr + c);
        acc[c + 0] = fmaf(xk, wv.x, acc[c + 0]);
        acc[c + 1] = fmaf(xk, wv.y, acc[c + 1]);
        acc[c + 2] = fmaf(xk, wv.z, acc[c + 2]);
        acc[c + 3] = fmaf(xk, wv.w, acc[c + 3]);
      }
    }
  }
  float d = dinv[i];
  float* yr = Y + (size_t)i * NCOL;
#pragma unroll
  for (int c = 0; c < NCOL; c += 4) {
    float4 o;
    o.x = acc[c + 0] * d; o.y = acc[c + 1] * d;
    o.z = acc[c + 2] * d; o.w = acc[c + 3] * d;
    *reinterpret_cast<float4*>(yr + c) = o;
  }
}

// ---------------- CSR gather-aggregate ----------------
// wave per dst node, lane = column. H[nd] = act(dinv[nd]*(Y[nd] + sum Y[src]) + b)

template<bool RELU>
__global__ void aggregate(const int* __restrict__ rowptr, const int* __restrict__ csr_src,
                          const float* __restrict__ Y, const float* __restrict__ dinv,
                          const float* __restrict__ bias, float* __restrict__ H, int n) {
  int nd = (blockIdx.x * blockDim.x + threadIdx.x) >> 6;
  if (nd >= n) return;
  nd = __builtin_amdgcn_readfirstlane(nd);   // wave-uniform -> scalar loads below
  int c = threadIdx.x & 63;
  int lo = rowptr[nd], hi = rowptr[nd + 1];
  float acc = Y[(size_t)nd * NCOL + c];      // self-loop term
  int p = lo;
  int hi4 = lo + ((hi - lo) & ~3);
  for (; p < hi4; p += 4) {
    int s0 = csr_src[p], s1 = csr_src[p + 1], s2 = csr_src[p + 2], s3 = csr_src[p + 3];
    float a0 = Y[(size_t)s0 * NCOL + c];
    float a1 = Y[(size_t)s1 * NCOL + c];
    float a2 = Y[(size_t)s2 * NCOL + c];
    float a3 = Y[(size_t)s3 * NCOL + c];
    acc += a0; acc += a1; acc += a2; acc += a3;
  }
  for (; p < hi; ++p) acc += Y[(size_t)csr_src[p] * NCOL + c];
  float v = fmaf(dinv[nd], acc, bias[c]);
  if (RELU) v = fmaxf(v, 0.f);
  H[(size_t)nd * NCOL + c] = v;
}

// ---------------- pooling: pool[g,:] += H over sorted batch runs ----------------

#define NPG 64

__global__ void pool_kernel(const float* __restrict__ H, const int* __restrict__ batch,
                            float* __restrict__ pool, int n) {
  int gid = (blockIdx.x * blockDim.x + threadIdx.x) >> 6;
  int c = threadIdx.x & 63;
  int n0 = gid * NPG;
  if (n0 >= n) return;
  int n1 = min(n0 + NPG, n);
  float acc = 0.f;
  int curg = batch[n0];
  for (int nd = n0; nd < n1; ++nd) {
    int g = batch[nd];
    if (g != curg) {
      atomicAdd(&pool[(size_t)curg * NCOL + c], acc);
      acc = 0.f;
      curg = g;
    }
    acc += H[(size_t)nd * NCOL + c];
  }
  atomicAdd(&pool[(size_t)curg * NCOL + c], acc);
}

// ---------------- final tiny GEMM: out = (pool/cnt) @ Wl + bl ----------------

__global__ void final_kernel(const float* __restrict__ pool, const int* __restrict__ startg,
                             const int* __restrict__ endg, const float* __restrict__ Wl,
                             const float* __restrict__ bl, float* __restrict__ out, int ng) {
  int t = threadIdx.x;
  if (t >= ng * 6) return;
  int g = t / 6, o = t % 6;
  float cntf = (float)(endg[g] - startg[g]);
  float inv = 1.0f / fmaxf(cntf, 1.0f);
  float s = 0.f;
#pragma unroll
  for (int c = 0; c < NCOL; ++c) s += pool[(size_t)g * NCOL + c] * Wl[c * 6 + o];
  out[t] = fmaf(s, inv, bl[o]);
}

// ---------------- launch ----------------

extern "C" void kernel_launch(void* const* d_in, const int* in_sizes, int n_in,
                              void* d_out, int out_size, void* d_ws, size_t ws_size,
                              hipStream_t stream) {
  const float* x    = (const float*)d_in[0];
  const int*   ei   = (const int*)d_in[1];
  const int*   batch= (const int*)d_in[2];
  const float* W1   = (const float*)d_in[3];
  const float* b1   = (const float*)d_in[4];
  const float* W2   = (const float*)d_in[5];
  const float* b2   = (const float*)d_in[6];
  const float* Wl   = (const float*)d_in[7];
  const float* bl   = (const float*)d_in[8];
  float* out = (float*)d_out;

  int n  = in_sizes[0] / 128;   // 100000
  int ne = in_sizes[1] / 2;     // 1600000
  int ng = out_size / 6;        // 64
  const int* srcI = ei;
  const int* dstI = ei + ne;

  char* w = (char*)d_ws;
  size_t o = 0;
  auto take = [&](size_t bytes) -> char* {
    char* p = w + o;
    o = (o + bytes + 255) & ~(size_t)255;
    return p;
  };
  float* dinv    = (float*)take((size_t)n * 4);
  int*   degi    = (int*)  take((size_t)n * 4);
  int*   cursor  = (int*)  take((size_t)n * 4);
  int*   rowptr  = (int*)  take((size_t)(n + 1) * 4);
  int*   csr_src = (int*)  take((size_t)ne * 4);
  float* Y       = (float*)take((size_t)n * NCOL * 4);
  float* H       = (float*)take((size_t)n * NCOL * 4);
  float* pool    = (float*)take(4096 * 4);
  int*   startg  = (int*)  take(64 * 4);
  int*   endg    = (int*)  take(64 * 4);
  int*   tsum    = (int*)  take(16384 * 4);
  int*   toff    = (int*)  take(16384 * 4);

  hipMemsetAsync(degi, 0, (size_t)n * 4, stream);
  hipMemsetAsync(pool, 0, 4096 * 4, stream);
  hipMemsetAsync(startg, 0, 64 * 4, stream);
  hipMemsetAsync(endg, 0, 64 * 4, stream);

  int nb256 = (n + 255) / 256;
  int nthreads = (n + SCAN_C - 1) / SCAN_C;
  int nbScan = (nthreads + 255) / 256;

  // CSR build (shared by both layers); XCD-partitioned atomics/writes
  deg_part<<<1024, 256, 0, stream>>>(dstI, degi, ne, n);
  bounds_kernel<<<nb256, 256, 0, stream>>>(batch, startg, endg, n);
  dinv_kernel<<<nb256, 256, 0, stream>>>(degi, dinv, n);
  scan_part<<<nbScan, 256, 0, stream>>>(degi, tsum, n, nthreads);
  scan_mid<<<1, 1024, 0, stream>>>(tsum, toff, nthreads);
  scan_fill<<<nbScan, 256, 0, stream>>>(degi, toff, rowptr, cursor, n, nthreads);
  csr_fill_part<<<1024, 256, 0, stream>>>(srcI, dstI, cursor, csr_src, ne, n);

  int nbAgg = (n * 64 + 255) / 256;

  // layer 1: Y = (x@W1)*dinv ; H = relu(dinv*(Y_self + sum Y[src]) + b1)
  gemm_scaled<128><<<nb256, 256, 0, stream>>>(x, W1, dinv, Y, n);
  aggregate<true><<<nbAgg, 256, 0, stream>>>(rowptr, csr_src, Y, dinv, b1, H, n);

  // layer 2: Y = (H@W2)*dinv ; H2 = dinv*(Y_self + sum Y[src]) + b2  (reuse H)
  gemm_scaled<64><<<nb256, 256, 0, stream>>>(H, W2, dinv, Y, n);
  aggregate<false><<<nbAgg, 256, 0, stream>>>(rowptr, csr_src, Y, dinv, b2, H, n);

  // pool + head
  int ngroups = (n + NPG - 1) / NPG;
  int pblocks = (ngroups * 64 + 255) / 256;
  pool_kernel<<<pblocks, 256, 0, stream>>>(H, batch, pool, n);
  final_kernel<<<1, 384, 0, stream>>>(pool, startg, endg, Wl, bl, out, ng);
}